// Round 10
// baseline (151.416 us; speedup 1.0000x reference)
//
#include <hip/hip_runtime.h>
#include <hip/hip_bf16.h>

typedef float f32x4 __attribute__((ext_vector_type(4)));
typedef short s16x8 __attribute__((ext_vector_type(8)));

__device__ __forceinline__ short f2bf(float f){
  union { float f; unsigned u; } v; v.f = f;
  unsigned u = v.u;
  u += 0x7fffu + ((u >> 16) & 1u);
  return (short)(u >> 16);
}

__device__ __forceinline__ f32x4 mfma16(s16x8 a, s16x8 b, f32x4 c){
  return __builtin_amdgcn_mfma_f32_16x16x32_bf16(a, b, c, 0, 0, 0);
}

__device__ __forceinline__ float fexp2(float x){
#if __has_builtin(__builtin_amdgcn_exp2f)
  return __builtin_amdgcn_exp2f(x);
#else
  float r; asm("v_exp_f32 %0, %1" : "=v"(r) : "v"(x)); return r;
#endif
}

// packed fp32x2 -> bf16x2 (RTNE), single instruction
__device__ __forceinline__ unsigned cvtpk(float lo, float hi){
  unsigned r; asm("v_cvt_pk_bf16_f32 %0, %1, %2" : "=v"(r) : "v"(lo), "v"(hi));
  return r;
}

// ---------------- K1: GroupNorm partial sums (1024 blocks) + weight cvt (merged) ----------------
__global__ __launch_bounds__(256) void gn_stats_cvt_k(const float* __restrict__ x,
                                                      const float* __restrict__ wq,
                                                      const float* __restrict__ wo,
                                                      float* __restrict__ part,
                                                      short* __restrict__ wq_bf,
                                                      short* __restrict__ wo_bf){
  int bx = blockIdx.x;
  if (bx >= 1024){
    int i = (bx - 1024)*256 + threadIdx.x;
    if (i < 384*256) wq_bf[i] = f2bf(wq[i]);
    if (i < 256*128) wo_bf[i] = f2bf(wo[i]);
    return;
  }
  const float4* base = ((const float4*)x) + (size_t)bx * 1024;
  float s = 0.f, s2 = 0.f;
  #pragma unroll
  for (int i = threadIdx.x; i < 1024; i += 256){
    float4 v = base[i];
    s  += v.x + v.y + v.z + v.w;
    s2 += v.x*v.x + v.y*v.y + v.z*v.z + v.w*v.w;
  }
  #pragma unroll
  for (int off = 32; off; off >>= 1){ s += __shfl_down(s, off); s2 += __shfl_down(s2, off); }
  __shared__ float ls[8];
  int wid = threadIdx.x >> 6;
  if ((threadIdx.x & 63) == 0){ ls[wid] = s; ls[4 + wid] = s2; }
  __syncthreads();
  if (threadIdx.x == 0){
    part[bx*2]     = ls[0]+ls[1]+ls[2]+ls[3];
    part[bx*2 + 1] = ls[4]+ls[5]+ls[6]+ls[7];
  }
}

// ---------------- K2: FUSED GroupNorm-apply + QKV GEMM ----------------
__global__ __launch_bounds__(256) void gn_qkv_k(const float* __restrict__ x,
                                                const float* __restrict__ part,
                                                const float* __restrict__ gamma,
                                                const float* __restrict__ beta,
                                                const short* __restrict__ wq_bf,
                                                short* __restrict__ q,
                                                short* __restrict__ k,
                                                short* __restrict__ vt){
  __shared__ float stg[64][33];
  __shared__ short xl[32*264];
  __shared__ float mstat[16];
  int b = blockIdx.y;
  int p0 = blockIdx.x * 32;
  int t = threadIdx.x;
  {
    int gi = t >> 5, sl = t & 31;
    float S  = part[((b*8+gi)*32 + sl)*2];
    float S2 = part[((b*8+gi)*32 + sl)*2 + 1];
    #pragma unroll
    for (int m = 16; m; m >>= 1){ S += __shfl_xor(S, m); S2 += __shfl_xor(S2, m); }
    if (sl == 0){
      float mn = S * (1.f/131072.f);
      mstat[gi]   = mn;
      mstat[8+gi] = rsqrtf(S2 * (1.f/131072.f) - mn*mn + 1e-5f);
    }
  }
  __syncthreads();
  int pj = t & 31, ci8 = t >> 5;
  for (int cc = 0; cc < 4; ++cc){
    #pragma unroll
    for (int r = 0; r < 8; ++r){
      int cl = r*8 + ci8;
      int c = cc*64 + cl;
      float v = x[((size_t)(b*256 + c))*4096 + p0 + pj];
      int gl = c >> 5;
      v = (v - mstat[gl]) * mstat[8+gl] * gamma[c] + beta[c];
      stg[cl][pj] = v;
    }
    __syncthreads();
    {
      s16x8 pack;
      #pragma unroll
      for (int i = 0; i < 8; ++i) pack[i] = f2bf(stg[ci8*8 + i][pj]);
      *(s16x8*)&xl[pj*264 + cc*64 + ci8*8] = pack;
    }
    __syncthreads();
  }
  int w = t >> 6, l = t & 63, l15 = l & 15, g = l >> 4;
  const float QSC = 0.17677669529663687f * 1.4426950408889634f;
  #pragma unroll
  for (int ot = 0; ot < 6; ++ot){
    int orow = w*96 + ot*16 + l15;
    const s16x8* wrow = (const s16x8*)(wq_bf + (size_t)orow * 256);
    s16x8 af[8];
    #pragma unroll
    for (int kk = 0; kk < 8; ++kk) af[kk] = wrow[kk*4 + g];
    #pragma unroll
    for (int pt = 0; pt < 2; ++pt){
      f32x4 acc = {0.f,0.f,0.f,0.f};
      #pragma unroll
      for (int kk = 0; kk < 8; ++kk)
        acc = mfma16(af[kk], *(const s16x8*)&xl[(pt*16+l15)*264 + kk*32 + g*8], acc);
      int p = p0 + pt*16 + l15;
      int pp = p & 31;
      int pos = ((pp>>2)&3)*8 + ((pp>>4)&1)*4 + (pp&3);
      int pperm = (p & ~31) | pos;
      #pragma unroll
      for (int e = 0; e < 4; ++e){
        int og = w*96 + ot*16 + 4*g + e;
        float v = acc[e];
        int sec = og >> 7;
        int oh = og & 127;
        int h = oh >> 5, d = oh & 31;
        size_t qk_idx = (((size_t)b*4 + h)*4096 + p)*32 + d;
        if (sec == 0)      q[qk_idx] = f2bf(v * QSC);
        else if (sec == 1) k[qk_idx] = f2bf(v);
        else vt[(((size_t)b*4 + h)*32 + d)*4096 + pperm] = f2bf(v);
      }
    }
  }
}

// ---------------- K4: flash attention v10 ----------------
// 4 waves/block, 32 q-rows shared; wave w owns j-quarter (32 tiles of 32 j).
// Identical inner loop to v9 (proven); smaller row-tile -> 20 KB LDS ->
// 8 blocks/CU = 32 waves/CU. Single-pass packed epilogue.
__global__ __launch_bounds__(256, 8) void flash_k(const short* __restrict__ q,
                                                  const short* __restrict__ k,
                                                  const short* __restrict__ vt,
                                                  short* __restrict__ at){
  __shared__ short ldsS[4*2560];          // 20480 B; wave region 2560 shorts
  int bid = blockIdx.x;
  int lin = (bid & 7)*256 + (bid >> 3);   // XCD swizzle (bijective: 2048 = 8*256)
  int bh = lin >> 7;                      // 0..15
  int rt  = lin & 127;                    // 32-row q tile
  int b = bh >> 2, h = bh & 3;
  int blkrow = rt * 32;
  int t = threadIdx.x;
  int w = t >> 6, l = t & 63, l15 = l & 15, g = l >> 4;

  const short* qb = q  + (size_t)bh * 4096 * 32;
  const short* kb = k  + (size_t)bh * 4096 * 32;
  const short* vb = vt + (size_t)bh * 32 * 4096;

  s16x8 qf[2];
  #pragma unroll
  for (int it = 0; it < 2; ++it)
    qf[it] = *(const s16x8*)(qb + (size_t)(blkrow + it*16 + l15)*32 + 8*g);

  int wbase = w * 2560;
  int rk = wbase + l15*40 + g*8;            // kf0; kf1 at +640
  int rv = wbase + 1280 + l15*40 + g*8;     // vf0; vf1 at +640
  int row = l >> 1, hi = (l & 1) * 16;
  int wk = wbase + row*40 + hi;
  int wv = wbase + 1280 + row*40 + hi;

  const short* kq = kb + (size_t)w*32768 + l*16;            // +1024 shorts / tile
  const short* vq = vb + (size_t)row*4096 + w*1024 + hi;    // +32 shorts / tile

  f32x4 o[2][2];
  float lsum[2];
  #pragma unroll
  for (int it = 0; it < 2; ++it){
    o[it][0] = (f32x4){0.f,0.f,0.f,0.f};
    o[it][1] = (f32x4){0.f,0.f,0.f,0.f};
    lsum[it] = 0.f;
  }
  const f32x4 zero = {0.f,0.f,0.f,0.f};

  s16x8 ka0, ka1, va0, va1;

#define FENCE() asm volatile("" ::: "memory")
#define KVLOAD() do{ ka0 = *(const s16x8*)kq; ka1 = *(const s16x8*)(kq + 8); kq += 1024; \
                     va0 = *(const s16x8*)vq; va1 = *(const s16x8*)(vq + 8); vq += 32; }while(0)
#define KVSTORE() do{ *(s16x8*)&ldsS[wk] = ka0; *(s16x8*)&ldsS[wk + 8] = ka1; \
                      *(s16x8*)&ldsS[wv] = va0; *(s16x8*)&ldsS[wv + 8] = va1; }while(0)
#define COMPUTE() do{ \
    s16x8 kf0 = *(const s16x8*)&ldsS[rk]; \
    s16x8 kf1 = *(const s16x8*)&ldsS[rk + 640]; \
    s16x8 vf0 = *(const s16x8*)&ldsS[rv]; \
    s16x8 vf1 = *(const s16x8*)&ldsS[rv + 640]; \
    _Pragma("unroll") \
    for (int it = 0; it < 2; ++it){ \
      f32x4 s0 = mfma16(kf0, qf[it], zero); \
      f32x4 s1 = mfma16(kf1, qf[it], zero); \
      float p0=fexp2(s0[0]), p1=fexp2(s0[1]), p2=fexp2(s0[2]), p3=fexp2(s0[3]); \
      float p4=fexp2(s1[0]), p5=fexp2(s1[1]), p6=fexp2(s1[2]), p7=fexp2(s1[3]); \
      lsum[it] += ((p0+p1)+(p2+p3)) + ((p4+p5)+(p6+p7)); \
      union { s16x8 v; unsigned u[4]; } pf; \
      pf.u[0] = cvtpk(p0,p1); pf.u[1] = cvtpk(p2,p3); \
      pf.u[2] = cvtpk(p4,p5); pf.u[3] = cvtpk(p6,p7); \
      o[it][0] = mfma16(pf.v, vf0, o[it][0]); \
      o[it][1] = mfma16(pf.v, vf1, o[it][1]); \
    } \
  }while(0)

  KVLOAD();
  KVSTORE();
  FENCE();
  for (int tt = 0; tt < 31; ++tt){
    KVLOAD();
    COMPUTE();
    FENCE();
    KVSTORE();
    FENCE();
  }
  COMPUTE();
#undef KVLOAD
#undef KVSTORE
#undef COMPUTE

  #pragma unroll
  for (int it = 0; it < 2; ++it){
    lsum[it] += __shfl_xor(lsum[it], 16);
    lsum[it] += __shfl_xor(lsum[it], 32);
  }

  FENCE();
  // ---- single-pass packed epilogue: [32][33] numerators + 32 sums per wave region ----
  float* cw = (float*)&ldsS[wbase];        // 1280 floats available; uses 1088
  #pragma unroll
  for (int it = 0; it < 2; ++it){
    #pragma unroll
    for (int e = 0; e < 4; ++e){
      int r = it*16 + 4*g + e;
      cw[r*33 + l15]      = o[it][0][e];
      cw[r*33 + 16 + l15] = o[it][1][e];
    }
    if (l < 16) cw[1056 + it*16 + l15] = lsum[it];
  }
  __syncthreads();
  int rr = t >> 3, a = t & 7;              // row 0..31, col-quad 0..7
  size_t rowbase = ((size_t)b*4096 + blkrow + rr)*128 + h*32;
  float den = 0.f, n0 = 0.f, n1 = 0.f, n2 = 0.f, n3 = 0.f;
  #pragma unroll
  for (int w2 = 0; w2 < 4; ++w2){
    const float* cr = (const float*)&ldsS[w2*2560];
    den += cr[1056 + rr];
    n0 += cr[rr*33 + a*4];
    n1 += cr[rr*33 + a*4 + 1];
    n2 += cr[rr*33 + a*4 + 2];
    n3 += cr[rr*33 + a*4 + 3];
  }
  float inv = 1.f / den;
  uint2 u; u.x = cvtpk(n0*inv, n1*inv); u.y = cvtpk(n2*inv, n3*inv);
  *(uint2*)(at + rowbase + a*4) = u;
}

// ---------------- K5: out GEMM + bias -> fp32 d_out ----------------
__global__ __launch_bounds__(256) void out_gemm_k(const short* __restrict__ wo_bf,
                                                  const short* __restrict__ at,
                                                  const float* __restrict__ b_out,
                                                  float* __restrict__ out){
  int b = blockIdx.z;
  int obase = blockIdx.y * 64;
  int pbase = blockIdx.x * 64;
  int t = threadIdx.x, w = t >> 6, l = t & 63, l15 = l & 15, g = l >> 4;
  int orow = obase + w*16 + l15;
  const s16x8* wrow = (const s16x8*)(wo_bf + (size_t)orow * 128);
  s16x8 af[4];
  #pragma unroll
  for (int kk = 0; kk < 4; ++kk) af[kk] = wrow[kk*4 + g];
  #pragma unroll
  for (int pt = 0; pt < 4; ++pt){
    int p = pbase + pt*16 + l15;
    const s16x8* xr = (const s16x8*)(at + ((size_t)b*4096 + p) * 128);
    f32x4 acc = {0.f,0.f,0.f,0.f};
    #pragma unroll
    for (int kk = 0; kk < 4; ++kk) acc = mfma16(af[kk], xr[kk*4 + g], acc);
    #pragma unroll
    for (int e = 0; e < 4; ++e){
      int og = obase + w*16 + 4*g + e;
      out[((size_t)b*256 + og)*4096 + p] = acc[e] + b_out[og];
    }
  }
}

extern "C" void kernel_launch(void* const* d_in, const int* in_sizes, int n_in,
                              void* d_out, int out_size, void* d_ws, size_t ws_size,
                              hipStream_t stream){
  const float* x     = (const float*)d_in[0];
  const float* w_qkv = (const float*)d_in[1];
  const float* w_out = (const float*)d_in[2];
  const float* b_out = (const float*)d_in[3];
  const float* gamma = (const float*)d_in[4];
  const float* beta  = (const float*)d_in[5];
  float* out = (float*)d_out;

  char* ws = (char*)d_ws;
  short* wq_bf = (short*)(ws);                 // 196608
  short* wo_bf = (short*)(ws + 196608);        // 65536   -> 262144
  short* qbuf  = (short*)(ws + 8652800);       // 4 MB
  short* kbuf  = (short*)(ws + 12847104);      // 4 MB
  short* vtbuf = (short*)(ws + 17041408);      // 4 MB
  short* atbuf = (short*)(ws + 21235712);      // 4 MB
  // part aliases atbuf's start: consumed by gn_qkv before flash writes atbuf
  float* part  = (float*)(ws + 21235712);      // 8 KB

  hipLaunchKernelGGL(gn_stats_cvt_k, dim3(1408),    dim3(256), 0, stream, x, w_qkv, w_out, part, wq_bf, wo_bf);
  hipLaunchKernelGGL(gn_qkv_k,       dim3(128,4),   dim3(256), 0, stream, x, part, gamma, beta, wq_bf, qbuf, kbuf, vtbuf);
  hipLaunchKernelGGL(flash_k,        dim3(2048),    dim3(256), 0, stream, qbuf, kbuf, vtbuf, atbuf);
  hipLaunchKernelGGL(out_gemm_k,     dim3(64,4,4),  dim3(256), 0, stream, wo_bf, atbuf, b_out, out);
}

// Round 11
// 108.714 us; speedup vs baseline: 1.3928x; 1.3928x over previous
//
#include <hip/hip_runtime.h>
#include <hip/hip_bf16.h>

typedef float f32x4 __attribute__((ext_vector_type(4)));
typedef short s16x8 __attribute__((ext_vector_type(8)));

__device__ __forceinline__ short f2bf(float f){
  union { float f; unsigned u; } v; v.f = f;
  unsigned u = v.u;
  u += 0x7fffu + ((u >> 16) & 1u);
  return (short)(u >> 16);
}

__device__ __forceinline__ f32x4 mfma16(s16x8 a, s16x8 b, f32x4 c){
  return __builtin_amdgcn_mfma_f32_16x16x32_bf16(a, b, c, 0, 0, 0);
}

__device__ __forceinline__ float fexp2(float x){
#if __has_builtin(__builtin_amdgcn_exp2f)
  return __builtin_amdgcn_exp2f(x);
#else
  float r; asm("v_exp_f32 %0, %1" : "=v"(r) : "v"(x)); return r;
#endif
}

// packed fp32x2 -> bf16x2 (RTNE), single instruction
__device__ __forceinline__ unsigned cvtpk(float lo, float hi){
  unsigned r; asm("v_cvt_pk_bf16_f32 %0, %1, %2" : "=v"(r) : "v"(lo), "v"(hi));
  return r;
}

// ---------------- K1: GroupNorm partial sums (1024 blocks) + weight cvt (merged) ----------------
__global__ __launch_bounds__(256) void gn_stats_cvt_k(const float* __restrict__ x,
                                                      const float* __restrict__ wq,
                                                      const float* __restrict__ wo,
                                                      float* __restrict__ part,
                                                      short* __restrict__ wq_bf,
                                                      short* __restrict__ wo_bf){
  int bx = blockIdx.x;
  if (bx >= 1024){
    int i = (bx - 1024)*256 + threadIdx.x;
    if (i < 384*256) wq_bf[i] = f2bf(wq[i]);
    if (i < 256*128) wo_bf[i] = f2bf(wo[i]);
    return;
  }
  const float4* base = ((const float4*)x) + (size_t)bx * 1024;
  float s = 0.f, s2 = 0.f;
  #pragma unroll
  for (int i = threadIdx.x; i < 1024; i += 256){
    float4 v = base[i];
    s  += v.x + v.y + v.z + v.w;
    s2 += v.x*v.x + v.y*v.y + v.z*v.z + v.w*v.w;
  }
  #pragma unroll
  for (int off = 32; off; off >>= 1){ s += __shfl_down(s, off); s2 += __shfl_down(s2, off); }
  __shared__ float ls[8];
  int wid = threadIdx.x >> 6;
  if ((threadIdx.x & 63) == 0){ ls[wid] = s; ls[4 + wid] = s2; }
  __syncthreads();
  if (threadIdx.x == 0){
    part[bx*2]     = ls[0]+ls[1]+ls[2]+ls[3];
    part[bx*2 + 1] = ls[4]+ls[5]+ls[6]+ls[7];
  }
}

// ---------------- K2: FUSED GroupNorm-apply + QKV GEMM ----------------
__global__ __launch_bounds__(256) void gn_qkv_k(const float* __restrict__ x,
                                                const float* __restrict__ part,
                                                const float* __restrict__ gamma,
                                                const float* __restrict__ beta,
                                                const short* __restrict__ wq_bf,
                                                short* __restrict__ q,
                                                short* __restrict__ k,
                                                short* __restrict__ vt){
  __shared__ float stg[64][33];
  __shared__ short xl[32*264];
  __shared__ float mstat[16];
  int b = blockIdx.y;
  int p0 = blockIdx.x * 32;
  int t = threadIdx.x;
  {
    int gi = t >> 5, sl = t & 31;
    float S  = part[((b*8+gi)*32 + sl)*2];
    float S2 = part[((b*8+gi)*32 + sl)*2 + 1];
    #pragma unroll
    for (int m = 16; m; m >>= 1){ S += __shfl_xor(S, m); S2 += __shfl_xor(S2, m); }
    if (sl == 0){
      float mn = S * (1.f/131072.f);
      mstat[gi]   = mn;
      mstat[8+gi] = rsqrtf(S2 * (1.f/131072.f) - mn*mn + 1e-5f);
    }
  }
  __syncthreads();
  int pj = t & 31, ci8 = t >> 5;
  for (int cc = 0; cc < 4; ++cc){
    #pragma unroll
    for (int r = 0; r < 8; ++r){
      int cl = r*8 + ci8;
      int c = cc*64 + cl;
      float v = x[((size_t)(b*256 + c))*4096 + p0 + pj];
      int gl = c >> 5;
      v = (v - mstat[gl]) * mstat[8+gl] * gamma[c] + beta[c];
      stg[cl][pj] = v;
    }
    __syncthreads();
    {
      s16x8 pack;
      #pragma unroll
      for (int i = 0; i < 8; ++i) pack[i] = f2bf(stg[ci8*8 + i][pj]);
      *(s16x8*)&xl[pj*264 + cc*64 + ci8*8] = pack;
    }
    __syncthreads();
  }
  int w = t >> 6, l = t & 63, l15 = l & 15, g = l >> 4;
  const float QSC = 0.17677669529663687f * 1.4426950408889634f;
  #pragma unroll
  for (int ot = 0; ot < 6; ++ot){
    int orow = w*96 + ot*16 + l15;
    const s16x8* wrow = (const s16x8*)(wq_bf + (size_t)orow * 256);
    s16x8 af[8];
    #pragma unroll
    for (int kk = 0; kk < 8; ++kk) af[kk] = wrow[kk*4 + g];
    #pragma unroll
    for (int pt = 0; pt < 2; ++pt){
      f32x4 acc = {0.f,0.f,0.f,0.f};
      #pragma unroll
      for (int kk = 0; kk < 8; ++kk)
        acc = mfma16(af[kk], *(const s16x8*)&xl[(pt*16+l15)*264 + kk*32 + g*8], acc);
      int p = p0 + pt*16 + l15;
      int pp = p & 31;
      int pos = ((pp>>2)&3)*8 + ((pp>>4)&1)*4 + (pp&3);
      int pperm = (p & ~31) | pos;
      #pragma unroll
      for (int e = 0; e < 4; ++e){
        int og = w*96 + ot*16 + 4*g + e;
        float v = acc[e];
        int sec = og >> 7;
        int oh = og & 127;
        int h = oh >> 5, d = oh & 31;
        size_t qk_idx = (((size_t)b*4 + h)*4096 + p)*32 + d;
        if (sec == 0)      q[qk_idx] = f2bf(v * QSC);
        else if (sec == 1) k[qk_idx] = f2bf(v);
        else vt[(((size_t)b*4 + h)*32 + d)*4096 + pperm] = f2bf(v);
      }
    }
  }
}

// ---------------- K4: flash attention v11 ----------------
// v10 structure (32 q-rows/block, 20 KB LDS -> 8 blocks/CU by LDS) but WITHOUT
// the forced 8-wave launch bound: (256,4) lets the allocator use ~56-64 VGPRs
// (no spill); hardware still co-resides 8 blocks when VGPR<=64.
__global__ __launch_bounds__(256, 4) void flash_k(const short* __restrict__ q,
                                                  const short* __restrict__ k,
                                                  const short* __restrict__ vt,
                                                  short* __restrict__ at){
  __shared__ short ldsS[4*2560];          // 20480 B; wave region 2560 shorts
  int bid = blockIdx.x;
  int lin = (bid & 7)*256 + (bid >> 3);   // XCD swizzle (bijective: 2048 = 8*256)
  int bh = lin >> 7;                      // 0..15
  int rt  = lin & 127;                    // 32-row q tile
  int b = bh >> 2, h = bh & 3;
  int blkrow = rt * 32;
  int t = threadIdx.x;
  int w = t >> 6, l = t & 63, l15 = l & 15, g = l >> 4;

  const short* qb = q  + (size_t)bh * 4096 * 32;
  const short* kb = k  + (size_t)bh * 4096 * 32;
  const short* vb = vt + (size_t)bh * 32 * 4096;

  s16x8 qf[2];
  #pragma unroll
  for (int it = 0; it < 2; ++it)
    qf[it] = *(const s16x8*)(qb + (size_t)(blkrow + it*16 + l15)*32 + 8*g);

  int wbase = w * 2560;
  int rk = wbase + l15*40 + g*8;            // kf0; kf1 at +640
  int rv = wbase + 1280 + l15*40 + g*8;     // vf0; vf1 at +640
  int row = l >> 1, hi = (l & 1) * 16;
  int wk = wbase + row*40 + hi;
  int wv = wbase + 1280 + row*40 + hi;

  const short* kq = kb + (size_t)w*32768 + l*16;            // +1024 shorts / tile
  const short* vq = vb + (size_t)row*4096 + w*1024 + hi;    // +32 shorts / tile

  f32x4 o[2][2];
  float lsum[2];
  #pragma unroll
  for (int it = 0; it < 2; ++it){
    o[it][0] = (f32x4){0.f,0.f,0.f,0.f};
    o[it][1] = (f32x4){0.f,0.f,0.f,0.f};
    lsum[it] = 0.f;
  }
  const f32x4 zero = {0.f,0.f,0.f,0.f};

  s16x8 ka0, ka1, va0, va1;

#define FENCE() asm volatile("" ::: "memory")
#define KVLOAD() do{ ka0 = *(const s16x8*)kq; ka1 = *(const s16x8*)(kq + 8); kq += 1024; \
                     va0 = *(const s16x8*)vq; va1 = *(const s16x8*)(vq + 8); vq += 32; }while(0)
#define KVSTORE() do{ *(s16x8*)&ldsS[wk] = ka0; *(s16x8*)&ldsS[wk + 8] = ka1; \
                      *(s16x8*)&ldsS[wv] = va0; *(s16x8*)&ldsS[wv + 8] = va1; }while(0)
#define COMPUTE() do{ \
    s16x8 kf0 = *(const s16x8*)&ldsS[rk]; \
    s16x8 kf1 = *(const s16x8*)&ldsS[rk + 640]; \
    s16x8 vf0 = *(const s16x8*)&ldsS[rv]; \
    s16x8 vf1 = *(const s16x8*)&ldsS[rv + 640]; \
    _Pragma("unroll") \
    for (int it = 0; it < 2; ++it){ \
      f32x4 s0 = mfma16(kf0, qf[it], zero); \
      f32x4 s1 = mfma16(kf1, qf[it], zero); \
      float p0=fexp2(s0[0]), p1=fexp2(s0[1]), p2=fexp2(s0[2]), p3=fexp2(s0[3]); \
      float p4=fexp2(s1[0]), p5=fexp2(s1[1]), p6=fexp2(s1[2]), p7=fexp2(s1[3]); \
      lsum[it] += ((p0+p1)+(p2+p3)) + ((p4+p5)+(p6+p7)); \
      union { s16x8 v; unsigned u[4]; } pf; \
      pf.u[0] = cvtpk(p0,p1); pf.u[1] = cvtpk(p2,p3); \
      pf.u[2] = cvtpk(p4,p5); pf.u[3] = cvtpk(p6,p7); \
      o[it][0] = mfma16(pf.v, vf0, o[it][0]); \
      o[it][1] = mfma16(pf.v, vf1, o[it][1]); \
    } \
  }while(0)

  KVLOAD();
  KVSTORE();
  FENCE();
  for (int tt = 0; tt < 31; ++tt){
    KVLOAD();
    COMPUTE();
    FENCE();
    KVSTORE();
    FENCE();
  }
  COMPUTE();
#undef KVLOAD
#undef KVSTORE
#undef COMPUTE

  #pragma unroll
  for (int it = 0; it < 2; ++it){
    lsum[it] += __shfl_xor(lsum[it], 16);
    lsum[it] += __shfl_xor(lsum[it], 32);
  }

  FENCE();
  // ---- single-pass packed epilogue: [32][33] numerators + 32 sums per wave region ----
  float* cw = (float*)&ldsS[wbase];        // 1280 floats available; uses 1088
  #pragma unroll
  for (int it = 0; it < 2; ++it){
    #pragma unroll
    for (int e = 0; e < 4; ++e){
      int r = it*16 + 4*g + e;
      cw[r*33 + l15]      = o[it][0][e];
      cw[r*33 + 16 + l15] = o[it][1][e];
    }
    if (l < 16) cw[1056 + it*16 + l15] = lsum[it];
  }
  __syncthreads();
  int rr = t >> 3, a = t & 7;              // row 0..31, col-quad 0..7
  size_t rowbase = ((size_t)b*4096 + blkrow + rr)*128 + h*32;
  float den = 0.f, n0 = 0.f, n1 = 0.f, n2 = 0.f, n3 = 0.f;
  #pragma unroll
  for (int w2 = 0; w2 < 4; ++w2){
    const float* cr = (const float*)&ldsS[w2*2560];
    den += cr[1056 + rr];
    n0 += cr[rr*33 + a*4];
    n1 += cr[rr*33 + a*4 + 1];
    n2 += cr[rr*33 + a*4 + 2];
    n3 += cr[rr*33 + a*4 + 3];
  }
  float inv = 1.f / den;
  uint2 u; u.x = cvtpk(n0*inv, n1*inv); u.y = cvtpk(n2*inv, n3*inv);
  *(uint2*)(at + rowbase + a*4) = u;
}

// ---------------- K5: out GEMM + bias -> fp32 d_out ----------------
__global__ __launch_bounds__(256) void out_gemm_k(const short* __restrict__ wo_bf,
                                                  const short* __restrict__ at,
                                                  const float* __restrict__ b_out,
                                                  float* __restrict__ out){
  int b = blockIdx.z;
  int obase = blockIdx.y * 64;
  int pbase = blockIdx.x * 64;
  int t = threadIdx.x, w = t >> 6, l = t & 63, l15 = l & 15, g = l >> 4;
  int orow = obase + w*16 + l15;
  const s16x8* wrow = (const s16x8*)(wo_bf + (size_t)orow * 128);
  s16x8 af[4];
  #pragma unroll
  for (int kk = 0; kk < 4; ++kk) af[kk] = wrow[kk*4 + g];
  #pragma unroll
  for (int pt = 0; pt < 4; ++pt){
    int p = pbase + pt*16 + l15;
    const s16x8* xr = (const s16x8*)(at + ((size_t)b*4096 + p) * 128);
    f32x4 acc = {0.f,0.f,0.f,0.f};
    #pragma unroll
    for (int kk = 0; kk < 4; ++kk) acc = mfma16(af[kk], xr[kk*4 + g], acc);
    #pragma unroll
    for (int e = 0; e < 4; ++e){
      int og = obase + w*16 + 4*g + e;
      out[((size_t)b*256 + og)*4096 + p] = acc[e] + b_out[og];
    }
  }
}

extern "C" void kernel_launch(void* const* d_in, const int* in_sizes, int n_in,
                              void* d_out, int out_size, void* d_ws, size_t ws_size,
                              hipStream_t stream){
  const float* x     = (const float*)d_in[0];
  const float* w_qkv = (const float*)d_in[1];
  const float* w_out = (const float*)d_in[2];
  const float* b_out = (const float*)d_in[3];
  const float* gamma = (const float*)d_in[4];
  const float* beta  = (const float*)d_in[5];
  float* out = (float*)d_out;

  char* ws = (char*)d_ws;
  short* wq_bf = (short*)(ws);                 // 196608
  short* wo_bf = (short*)(ws + 196608);        // 65536   -> 262144
  short* qbuf  = (short*)(ws + 8652800);       // 4 MB
  short* kbuf  = (short*)(ws + 12847104);      // 4 MB
  short* vtbuf = (short*)(ws + 17041408);      // 4 MB
  short* atbuf = (short*)(ws + 21235712);      // 4 MB
  // part aliases atbuf's start: consumed by gn_qkv before flash writes atbuf
  float* part  = (float*)(ws + 21235712);      // 8 KB

  hipLaunchKernelGGL(gn_stats_cvt_k, dim3(1408),    dim3(256), 0, stream, x, w_qkv, w_out, part, wq_bf, wo_bf);
  hipLaunchKernelGGL(gn_qkv_k,       dim3(128,4),   dim3(256), 0, stream, x, part, gamma, beta, wq_bf, qbuf, kbuf, vtbuf);
  hipLaunchKernelGGL(flash_k,        dim3(2048),    dim3(256), 0, stream, qbuf, kbuf, vtbuf, atbuf);
  hipLaunchKernelGGL(out_gemm_k,     dim3(64,4,4),  dim3(256), 0, stream, wo_bf, atbuf, b_out, out);
}

// Round 13
// 88.465 us; speedup vs baseline: 1.7116x; 1.2289x over previous
//
#include <hip/hip_runtime.h>
#include <hip/hip_bf16.h>

typedef float f32x4 __attribute__((ext_vector_type(4)));
typedef short s16x8 __attribute__((ext_vector_type(8)));

__device__ __forceinline__ short f2bf(float f){
  union { float f; unsigned u; } v; v.f = f;
  unsigned u = v.u;
  u += 0x7fffu + ((u >> 16) & 1u);
  return (short)(u >> 16);
}

__device__ __forceinline__ f32x4 mfma16(s16x8 a, s16x8 b, f32x4 c){
  return __builtin_amdgcn_mfma_f32_16x16x32_bf16(a, b, c, 0, 0, 0);
}

__device__ __forceinline__ float fexp2(float x){
#if __has_builtin(__builtin_amdgcn_exp2f)
  return __builtin_amdgcn_exp2f(x);
#else
  float r; asm("v_exp_f32 %0, %1" : "=v"(r) : "v"(x)); return r;
#endif
}

// packed fp32x2 -> bf16x2 (RTNE), single instruction
__device__ __forceinline__ unsigned cvtpk(float lo, float hi){
  unsigned r; asm("v_cvt_pk_bf16_f32 %0, %1, %2" : "=v"(r) : "v"(lo), "v"(hi));
  return r;
}

// ---------------- K1: GroupNorm partial sums (1024 blocks) + weight cvt (merged) ----------------
__global__ __launch_bounds__(256) void gn_stats_cvt_k(const float* __restrict__ x,
                                                      const float* __restrict__ wq,
                                                      const float* __restrict__ wo,
                                                      float* __restrict__ part,
                                                      short* __restrict__ wq_bf,
                                                      short* __restrict__ wo_bf){
  int bx = blockIdx.x;
  if (bx >= 1024){
    int i = (bx - 1024)*256 + threadIdx.x;
    if (i < 384*256) wq_bf[i] = f2bf(wq[i]);
    if (i < 256*128) wo_bf[i] = f2bf(wo[i]);
    return;
  }
  const float4* base = ((const float4*)x) + (size_t)bx * 1024;
  float s = 0.f, s2 = 0.f;
  #pragma unroll
  for (int i = threadIdx.x; i < 1024; i += 256){
    float4 v = base[i];
    s  += v.x + v.y + v.z + v.w;
    s2 += v.x*v.x + v.y*v.y + v.z*v.z + v.w*v.w;
  }
  #pragma unroll
  for (int off = 32; off; off >>= 1){ s += __shfl_down(s, off); s2 += __shfl_down(s2, off); }
  __shared__ float ls[8];
  int wid = threadIdx.x >> 6;
  if ((threadIdx.x & 63) == 0){ ls[wid] = s; ls[4 + wid] = s2; }
  __syncthreads();
  if (threadIdx.x == 0){
    part[bx*2]     = ls[0]+ls[1]+ls[2]+ls[3];
    part[bx*2 + 1] = ls[4]+ls[5]+ls[6]+ls[7];
  }
}

// ---------------- K2: FUSED GroupNorm-apply + QKV GEMM ----------------
__global__ __launch_bounds__(256) void gn_qkv_k(const float* __restrict__ x,
                                                const float* __restrict__ part,
                                                const float* __restrict__ gamma,
                                                const float* __restrict__ beta,
                                                const short* __restrict__ wq_bf,
                                                short* __restrict__ q,
                                                short* __restrict__ k,
                                                short* __restrict__ vt){
  __shared__ float stg[64][33];
  __shared__ short xl[32*264];
  __shared__ float mstat[16];
  int b = blockIdx.y;
  int p0 = blockIdx.x * 32;
  int t = threadIdx.x;
  {
    int gi = t >> 5, sl = t & 31;
    float S  = part[((b*8+gi)*32 + sl)*2];
    float S2 = part[((b*8+gi)*32 + sl)*2 + 1];
    #pragma unroll
    for (int m = 16; m; m >>= 1){ S += __shfl_xor(S, m); S2 += __shfl_xor(S2, m); }
    if (sl == 0){
      float mn = S * (1.f/131072.f);
      mstat[gi]   = mn;
      mstat[8+gi] = rsqrtf(S2 * (1.f/131072.f) - mn*mn + 1e-5f);
    }
  }
  __syncthreads();
  int pj = t & 31, ci8 = t >> 5;
  for (int cc = 0; cc < 4; ++cc){
    #pragma unroll
    for (int r = 0; r < 8; ++r){
      int cl = r*8 + ci8;
      int c = cc*64 + cl;
      float v = x[((size_t)(b*256 + c))*4096 + p0 + pj];
      int gl = c >> 5;
      v = (v - mstat[gl]) * mstat[8+gl] * gamma[c] + beta[c];
      stg[cl][pj] = v;
    }
    __syncthreads();
    {
      s16x8 pack;
      #pragma unroll
      for (int i = 0; i < 8; ++i) pack[i] = f2bf(stg[ci8*8 + i][pj]);
      *(s16x8*)&xl[pj*264 + cc*64 + ci8*8] = pack;
    }
    __syncthreads();
  }
  int w = t >> 6, l = t & 63, l15 = l & 15, g = l >> 4;
  const float QSC = 0.17677669529663687f * 1.4426950408889634f;
  #pragma unroll
  for (int ot = 0; ot < 6; ++ot){
    int orow = w*96 + ot*16 + l15;
    const s16x8* wrow = (const s16x8*)(wq_bf + (size_t)orow * 256);
    s16x8 af[8];
    #pragma unroll
    for (int kk = 0; kk < 8; ++kk) af[kk] = wrow[kk*4 + g];
    #pragma unroll
    for (int pt = 0; pt < 2; ++pt){
      f32x4 acc = {0.f,0.f,0.f,0.f};
      #pragma unroll
      for (int kk = 0; kk < 8; ++kk)
        acc = mfma16(af[kk], *(const s16x8*)&xl[(pt*16+l15)*264 + kk*32 + g*8], acc);
      int p = p0 + pt*16 + l15;
      int pp = p & 31;
      int pos = ((pp>>2)&3)*8 + ((pp>>4)&1)*4 + (pp&3);
      int pperm = (p & ~31) | pos;
      #pragma unroll
      for (int e = 0; e < 4; ++e){
        int og = w*96 + ot*16 + 4*g + e;
        float v = acc[e];
        int sec = og >> 7;
        int oh = og & 127;
        int h = oh >> 5, d = oh & 31;
        size_t qk_idx = (((size_t)b*4 + h)*4096 + p)*32 + d;
        if (sec == 0)      q[qk_idx] = f2bf(v * QSC);
        else if (sec == 1) k[qk_idx] = f2bf(v);
        else vt[(((size_t)b*4 + h)*32 + d)*4096 + pperm] = f2bf(v);
      }
    }
  }
}

// ---------------- K4: flash attention v13 ----------------
// Round-9 structure (proven): 4 waves/block, 64 q-rows shared; wave w owns
// j-quarter (32 tiles of 32 j); per-wave single-buffer padded LDS staging,
// no main-loop barriers. ONE change: denominator via ones-MFMA (v5-proven)
// instead of VALU lsum adds + shuffles.
__global__ __launch_bounds__(256, 4) void flash_k(const short* __restrict__ q,
                                                  const short* __restrict__ k,
                                                  const short* __restrict__ vt,
                                                  short* __restrict__ at){
  __shared__ short ldsS[4*4096];
  int bid = blockIdx.x;
  int lin = (bid & 7)*128 + (bid >> 3);   // XCD swizzle (bijective: 1024 = 8*128)
  int bh = lin >> 6;
  int rt  = lin & 63;
  int b = bh >> 2, h = bh & 3;
  int blkrow = rt * 64;
  int t = threadIdx.x;
  int w = t >> 6, l = t & 63, l15 = l & 15, g = l >> 4;

  const short* qb = q  + (size_t)bh * 4096 * 32;
  const short* kb = k  + (size_t)bh * 4096 * 32;
  const short* vb = vt + (size_t)bh * 32 * 4096;

  s16x8 qf[4];
  #pragma unroll
  for (int it = 0; it < 4; ++it)
    qf[it] = *(const s16x8*)(qb + (size_t)(blkrow + it*16 + l15)*32 + 8*g);

  const short ONE = (short)0x3F80;
  const s16x8 ones = {ONE,ONE,ONE,ONE,ONE,ONE,ONE,ONE};

  int wbase = w * 4096;
  int rk = wbase + l15*40 + g*8;
  int rv = wbase + 1280 + l15*40 + g*8;
  int row = l >> 1, hi = (l & 1) * 16;
  int wk = wbase + row*40 + hi;
  int wv = wbase + 1280 + row*40 + hi;

  const short* kq = kb + (size_t)w*32768 + l*16;
  const short* vq = vb + (size_t)row*4096 + w*1024 + hi;

  f32x4 o[4][2], osum[4];
  #pragma unroll
  for (int it = 0; it < 4; ++it){
    o[it][0] = (f32x4){0.f,0.f,0.f,0.f};
    o[it][1] = (f32x4){0.f,0.f,0.f,0.f};
    osum[it] = (f32x4){0.f,0.f,0.f,0.f};
  }
  const f32x4 zero = {0.f,0.f,0.f,0.f};

  s16x8 ka0, ka1, va0, va1;

#define FENCE() asm volatile("" ::: "memory")
#define KVLOAD() do{ ka0 = *(const s16x8*)kq; ka1 = *(const s16x8*)(kq + 8); kq += 1024; \
                     va0 = *(const s16x8*)vq; va1 = *(const s16x8*)(vq + 8); vq += 32; }while(0)
#define KVSTORE() do{ *(s16x8*)&ldsS[wk] = ka0; *(s16x8*)&ldsS[wk + 8] = ka1; \
                      *(s16x8*)&ldsS[wv] = va0; *(s16x8*)&ldsS[wv + 8] = va1; }while(0)
#define COMPUTE() do{ \
    s16x8 kf0 = *(const s16x8*)&ldsS[rk]; \
    s16x8 kf1 = *(const s16x8*)&ldsS[rk + 640]; \
    s16x8 vf0 = *(const s16x8*)&ldsS[rv]; \
    s16x8 vf1 = *(const s16x8*)&ldsS[rv + 640]; \
    _Pragma("unroll") \
    for (int it = 0; it < 4; ++it){ \
      f32x4 s0 = mfma16(kf0, qf[it], zero); \
      f32x4 s1 = mfma16(kf1, qf[it], zero); \
      float p0=fexp2(s0[0]), p1=fexp2(s0[1]), p2=fexp2(s0[2]), p3=fexp2(s0[3]); \
      float p4=fexp2(s1[0]), p5=fexp2(s1[1]), p6=fexp2(s1[2]), p7=fexp2(s1[3]); \
      union { s16x8 v; unsigned u[4]; } pf; \
      pf.u[0] = cvtpk(p0,p1); pf.u[1] = cvtpk(p2,p3); \
      pf.u[2] = cvtpk(p4,p5); pf.u[3] = cvtpk(p6,p7); \
      o[it][0] = mfma16(pf.v, vf0, o[it][0]); \
      o[it][1] = mfma16(pf.v, vf1, o[it][1]); \
      osum[it] = mfma16(pf.v, ones, osum[it]); \
    } \
  }while(0)

  KVLOAD();
  KVSTORE();
  FENCE();
  for (int tt = 0; tt < 31; ++tt){
    KVLOAD();
    COMPUTE();
    FENCE();
    KVSTORE();
    FENCE();
  }
  COMPUTE();
#undef KVLOAD
#undef KVSTORE
#undef COMPUTE

  FENCE();
  // ---- 2-pass packed epilogue (proven v9 structure); denominators from osum ----
  float* cw = (float*)&ldsS[wbase];        // 2048 floats per wave region
  #pragma unroll
  for (int it = 0; it < 4; ++it){
    #pragma unroll
    for (int e = 0; e < 4; ++e){
      int r = it*16 + 4*g + e;
      cw[r*17 + l15] = o[it][0][e];
      if (l15 == 0) cw[1088 + r] = osum[it][e];
    }
  }
  __syncthreads();
  int rr = t >> 2, a = t & 3;
  size_t rowbase = ((size_t)b*4096 + blkrow + rr)*128 + h*32;
  float den = 0.f, n0 = 0.f, n1 = 0.f, n2 = 0.f, n3 = 0.f;
  #pragma unroll
  for (int w2 = 0; w2 < 4; ++w2){
    const float* cr = (const float*)&ldsS[w2*4096];
    den += cr[1088 + rr];
    n0 += cr[rr*17 + a*4];
    n1 += cr[rr*17 + a*4 + 1];
    n2 += cr[rr*17 + a*4 + 2];
    n3 += cr[rr*17 + a*4 + 3];
  }
  float inv = 1.f / den;
  { uint2 u; u.x = cvtpk(n0*inv, n1*inv); u.y = cvtpk(n2*inv, n3*inv);
    *(uint2*)(at + rowbase + a*4) = u; }
  __syncthreads();
  #pragma unroll
  for (int it = 0; it < 4; ++it){
    #pragma unroll
    for (int e = 0; e < 4; ++e){
      int r = it*16 + 4*g + e;
      cw[r*17 + l15] = o[it][1][e];
    }
  }
  __syncthreads();
  n0 = 0.f; n1 = 0.f; n2 = 0.f; n3 = 0.f;
  #pragma unroll
  for (int w2 = 0; w2 < 4; ++w2){
    const float* cr = (const float*)&ldsS[w2*4096];
    n0 += cr[rr*17 + a*4];
    n1 += cr[rr*17 + a*4 + 1];
    n2 += cr[rr*17 + a*4 + 2];
    n3 += cr[rr*17 + a*4 + 3];
  }
  { uint2 u; u.x = cvtpk(n0*inv, n1*inv); u.y = cvtpk(n2*inv, n3*inv);
    *(uint2*)(at + rowbase + 16 + a*4) = u; }
}

// ---------------- K5: out GEMM + bias -> fp32 d_out ----------------
__global__ __launch_bounds__(256) void out_gemm_k(const short* __restrict__ wo_bf,
                                                  const short* __restrict__ at,
                                                  const float* __restrict__ b_out,
                                                  float* __restrict__ out){
  int b = blockIdx.z;
  int obase = blockIdx.y * 64;
  int pbase = blockIdx.x * 64;
  int t = threadIdx.x, w = t >> 6, l = t & 63, l15 = l & 15, g = l >> 4;
  int orow = obase + w*16 + l15;
  const s16x8* wrow = (const s16x8*)(wo_bf + (size_t)orow * 128);
  s16x8 af[4];
  #pragma unroll
  for (int kk = 0; kk < 4; ++kk) af[kk] = wrow[kk*4 + g];
  #pragma unroll
  for (int pt = 0; pt < 4; ++pt){
    int p = pbase + pt*16 + l15;
    const s16x8* xr = (const s16x8*)(at + ((size_t)b*4096 + p) * 128);
    f32x4 acc = {0.f,0.f,0.f,0.f};
    #pragma unroll
    for (int kk = 0; kk < 4; ++kk) acc = mfma16(af[kk], xr[kk*4 + g], acc);
    #pragma unroll
    for (int e = 0; e < 4; ++e){
      int og = obase + w*16 + 4*g + e;
      out[((size_t)b*256 + og)*4096 + p] = acc[e] + b_out[og];
    }
  }
}

extern "C" void kernel_launch(void* const* d_in, const int* in_sizes, int n_in,
                              void* d_out, int out_size, void* d_ws, size_t ws_size,
                              hipStream_t stream){
  const float* x     = (const float*)d_in[0];
  const float* w_qkv = (const float*)d_in[1];
  const float* w_out = (const float*)d_in[2];
  const float* b_out = (const float*)d_in[3];
  const float* gamma = (const float*)d_in[4];
  const float* beta  = (const float*)d_in[5];
  float* out = (float*)d_out;

  char* ws = (char*)d_ws;
  short* wq_bf = (short*)(ws);                 // 196608
  short* wo_bf = (short*)(ws + 196608);        // 65536   -> 262144
  short* qbuf  = (short*)(ws + 8652800);       // 4 MB
  short* kbuf  = (short*)(ws + 12847104);      // 4 MB
  short* vtbuf = (short*)(ws + 17041408);      // 4 MB
  short* atbuf = (short*)(ws + 21235712);      // 4 MB
  // part aliases atbuf's start: consumed by gn_qkv before flash writes atbuf
  float* part  = (float*)(ws + 21235712);      // 8 KB

  hipLaunchKernelGGL(gn_stats_cvt_k, dim3(1408),    dim3(256), 0, stream, x, w_qkv, w_out, part, wq_bf, wo_bf);
  hipLaunchKernelGGL(gn_qkv_k,       dim3(128,4),   dim3(256), 0, stream, x, part, gamma, beta, wq_bf, qbuf, kbuf, vtbuf);
  hipLaunchKernelGGL(flash_k,        dim3(1024),    dim3(256), 0, stream, qbuf, kbuf, vtbuf, atbuf);
  hipLaunchKernelGGL(out_gemm_k,     dim3(64,4,4),  dim3(256), 0, stream, wo_bf, atbuf, b_out, out);
}